// Round 8
// baseline (280.844 us; speedup 1.0000x reference)
//
#include <hip/hip_runtime.h>
#include <math.h>

#define LNUM 3
#define ENUM 8
#define BSZ 256
#define NSZ 1024
#define DSZ 512
#define SSZ 128   // DS
#define HPAD 516  // padded h row in LDS (bank-conflict-free tok stride)

typedef float f32x4 __attribute__((ext_vector_type(4)));

// ============ K_gate: h reconstruct + gating + lists + passthrough ============
// grid = 32 blocks x 256 thr; block handles 8 tokens.
__global__ __launch_bounds__(256) void gate_kernel(
    const float* __restrict__ h_base,   // token (l=0) or hbuf
    const float* __restrict__ y_in,     // ybuf [2][B][D] gated, or null (l=0)
    const float* __restrict__ gates_prev,// [B][8] or null
    const float* __restrict__ Dsk_prev, // [8][D] or null
    float* __restrict__ hbuf,           // out: reconstructed h (in-place ok)
    const float* __restrict__ Wg_l,     // [D][8]
    const float* __restrict__ bg_l,     // [8]
    const float* __restrict__ st_l,     // [8][B][DS]
    float* __restrict__ os_l,           // [8][B][DS]
    float* __restrict__ gates_l,        // [B][8]
    int* __restrict__ cnt_l,            // [8]
    int* __restrict__ list_l,           // [8][256]
    float* __restrict__ acc_probs,      // [8]
    float* __restrict__ acc_sel)        // [8]
{
    const int t = threadIdx.x;
    const int b0 = blockIdx.x * 8;

    __shared__ float h_s[8 * HPAD];
    __shared__ float wg_s[DSZ * ENUM];     // 16 KB
    __shared__ float dsk_s[ENUM * DSZ];    // 16 KB
    __shared__ float gprev_s[8 * ENUM];
    __shared__ float lgp[256];
    __shared__ float lg_s[8][ENUM];
    __shared__ int   sel_s[8][2];
    __shared__ float psum[ENUM], ssum[ENUM];

    // stage Wg (1024 quads), Dsk_prev, gates_prev
    for (int i = t; i < 1024; i += 256) ((f32x4*)wg_s)[i] = ((const f32x4*)Wg_l)[i];
    if (y_in) {
        for (int i = t; i < 1024; i += 256) ((f32x4*)dsk_s)[i] = ((const f32x4*)Dsk_prev)[i];
        if (t < 64) gprev_s[t] = gates_prev[b0 * ENUM + t];
    }
    if (t < ENUM) { psum[t] = 0.f; ssum[t] = 0.f; }
    __syncthreads();

    // reconstruct h: 8 tok x 128 quads
    for (int i = t; i < 1024; i += 256) {
        const int tok = i >> 7, dq = i & 127;
        const int b = b0 + tok;
        f32x4 hq = ((const f32x4*)(h_base + (size_t)b * DSZ))[dq];
        if (y_in) {
            f32x4 w = {0.f, 0.f, 0.f, 0.f};
            #pragma unroll
            for (int e = 0; e < ENUM; ++e)
                w += ((const f32x4*)(dsk_s + e * DSZ))[dq] * gprev_s[tok * ENUM + e];
            hq = hq + hq * w
               + ((const f32x4*)(y_in + (size_t)b * DSZ))[dq]
               + ((const f32x4*)(y_in + (size_t)(BSZ + b) * DSZ))[dq];
        }
        *(f32x4*)(h_s + tok * HPAD + dq * 4) = hq;
        ((f32x4*)(hbuf + (size_t)b * DSZ))[dq] = hq;
    }
    __syncthreads();

    // gate dots: t -> (tok = t>>5, e = (t>>2)&7, qt = t&3), quarter-K partials
    {
        const int tok = t >> 5, e = (t >> 2) & 7, qt = t & 3;
        const float* hp = h_s + tok * HPAD + qt * 128;
        const float* wp = wg_s + (qt * 128) * ENUM + e;
        float p = 0.f;
        #pragma unroll 8
        for (int d = 0; d < 128; ++d) p = fmaf(hp[d], wp[d * ENUM], p);
        lgp[t] = p;
    }
    __syncthreads();
    if (t < 64) {
        const int tok = t >> 3, e = t & 7;
        lg_s[tok][e] = lgp[tok * 32 + e * 4] + lgp[tok * 32 + e * 4 + 1]
                     + lgp[tok * 32 + e * 4 + 2] + lgp[tok * 32 + e * 4 + 3] + bg_l[e];
    }
    __syncthreads();

    // per-token softmax + top2 (threads 0..7)
    if (t < 8) {
        const int b = b0 + t;
        float probs[ENUM];
        float mx = lg_s[t][0];
        for (int e = 1; e < ENUM; ++e) mx = fmaxf(mx, lg_s[t][e]);
        float ss = 0.f;
        for (int e = 0; e < ENUM; ++e) { probs[e] = expf(lg_s[t][e] - mx); ss += probs[e]; }
        const float sinv = 1.f / ss;
        for (int e = 0; e < ENUM; ++e) probs[e] *= sinv;
        int i0 = 0;
        for (int e = 1; e < ENUM; ++e) if (probs[e] > probs[i0]) i0 = e;
        int i1 = -1;
        for (int e = 0; e < ENUM; ++e) {
            if (e == i0) continue;
            if (i1 < 0 || probs[e] > probs[i1]) i1 = e;
        }
        const float gs = 1.f / (probs[i0] + probs[i1]);
        for (int e = 0; e < ENUM; ++e) {
            float g = 0.f;
            if (e == i0) g = probs[i0] * gs;
            else if (e == i1) g = probs[i1] * gs;
            gates_l[b * ENUM + e] = g;
            atomicAdd(&psum[e], probs[e]);
        }
        atomicAdd(&ssum[i0], 1.0f);
        atomicAdd(&ssum[i1], 1.0f);
        sel_s[t][0] = i0; sel_s[t][1] = i1;
        const int idx0 = atomicAdd(&cnt_l[i0], 1);
        list_l[i0 * 256 + idx0] = b;            // slot 0
        const int idx1 = atomicAdd(&cnt_l[i1], 1);
        list_l[i1 * 256 + idx1] = b | (1 << 8); // slot 1
    }
    __syncthreads();
    if (t < ENUM) {
        atomicAdd(&acc_probs[t], psum[t]);
        atomicAdd(&acc_sel[t], ssum[t]);
    }

    // passthrough out_states for unselected: 8e x 8tok x 32sq = 2048 quads
    for (int i = t; i < 2048; i += 256) {
        const int e = i >> 8, tok = (i >> 5) & 7, sq = i & 31;
        if (e == sel_s[tok][0] || e == sel_s[tok][1]) continue;
        const size_t off = ((size_t)e * BSZ + (b0 + tok)) * SSZ;
        ((f32x4*)(os_l + off))[sq] = ((const f32x4*)(st_l + off))[sq];
    }
}

// ============ K_snew: s_new for selected rows -> out_states ============
// grid = 256 (e = bid&7, tile = (bid>>3)&7, sc = bid>>6), 1024 thr.
// thread (tok = t>>5, s = t&31): full-K=512 dot, col = sc*32+s.
__global__ __launch_bounds__(1024, 1) void snew_kernel(
    const float* __restrict__ hbuf,     // [B][D]
    const float* __restrict__ A_l,      // [8][DS]
    const float* __restrict__ Bin_l,    // [8][D][DS]
    const float* __restrict__ st_l,     // [8][B][DS]
    float* __restrict__ os_l,           // [8][B][DS]
    const int* __restrict__ cnt_l,
    const int* __restrict__ list_l)
{
    const int e = blockIdx.x & 7, tile = (blockIdx.x >> 3) & 7, sc = blockIdx.x >> 6;
    const int ntot = cnt_l[e];
    const int base = tile * 32;
    if (base >= ntot) return;
    const int nt = min(32, ntot - base);
    const int t = threadIdx.x;

    __shared__ float h_s[32][DSZ];   // 64 KB
    __shared__ int toks[32];

    if (t < 32) toks[t] = (t < nt) ? (list_l[e * 256 + base + t] & 255) : 0;
    __syncthreads();
    for (int i = t; i < 32 * 128; i += 1024) {
        const int tok = i >> 7, dq = i & 127;
        ((f32x4*)h_s[tok])[dq] = ((const f32x4*)(hbuf + (size_t)toks[tok] * DSZ))[dq];
    }
    __syncthreads();

    const int tok = t >> 5, s = t & 31;
    if (tok < nt) {
        const int sglob = sc * 32 + s;
        const float* hp = h_s[tok];
        const float* Bp = Bin_l + (size_t)e * DSZ * SSZ + sglob;
        float a0 = 0.f, a1 = 0.f, a2 = 0.f, a3 = 0.f;
        #pragma unroll 8
        for (int d = 0; d < 512; d += 4) {
            a0 = fmaf(hp[d + 0], Bp[(size_t)(d + 0) * SSZ], a0);
            a1 = fmaf(hp[d + 1], Bp[(size_t)(d + 1) * SSZ], a1);
            a2 = fmaf(hp[d + 2], Bp[(size_t)(d + 2) * SSZ], a2);
            a3 = fmaf(hp[d + 3], Bp[(size_t)(d + 3) * SSZ], a3);
        }
        const float sum = (a0 + a1) + (a2 + a3);
        const int b = toks[tok];
        const float a = A_l[e * SSZ + sglob];
        const float decay = 1.f / (1.f + expf(-a));
        const float sn = decay * st_l[((size_t)e * BSZ + b) * SSZ + sglob] + sum;
        os_l[((size_t)e * BSZ + b) * SSZ + sglob] = sn;
    }
}

// ============ K_y: gated y slices -> ybuf[slot] ============
// grid = 256 (e, tile, dc = bid>>6), 1024 thr.
// thread (tok = t>>5, dq = t&31): full-K=128 f32x4 dot, cols dc*128 + dq*4.
__global__ __launch_bounds__(1024, 1) void y_kernel(
    const float* __restrict__ os_l,     // [8][B][DS]  (s_new for selected)
    const float* __restrict__ Cou_l,    // [8][DS][D]
    const float* __restrict__ gates_l,  // [B][8]
    float* __restrict__ ybuf,           // [2][B][D]
    const int* __restrict__ cnt_l,
    const int* __restrict__ list_l)
{
    const int e = blockIdx.x & 7, tile = (blockIdx.x >> 3) & 7, dc = blockIdx.x >> 6;
    const int ntot = cnt_l[e];
    const int base = tile * 32;
    if (base >= ntot) return;
    const int nt = min(32, ntot - base);
    const int t = threadIdx.x;

    __shared__ float sn_s[32][SSZ];   // 16 KB
    __shared__ int toks[32], slots[32];
    __shared__ float g_s[32];

    if (t < 32) {
        const int entry = (t < nt) ? list_l[e * 256 + base + t] : 0;
        toks[t] = entry & 255;
        slots[t] = (entry >> 8) & 1;
        g_s[t] = gates_l[(entry & 255) * ENUM + e];
    }
    __syncthreads();
    {   // stage s_new rows: 32 tok x 32 quads = 1024
        const int tok = t >> 5, sq = t & 31;
        ((f32x4*)sn_s[tok])[sq] =
            ((const f32x4*)(os_l + ((size_t)e * BSZ + toks[tok]) * SSZ))[sq];
    }
    __syncthreads();

    const int tok = t >> 5, dq = t & 31;
    if (tok < nt) {
        const int dcb = dc * 128;
        const float* Cp = Cou_l + (size_t)e * SSZ * DSZ + dcb + dq * 4;
        const float* snp = sn_s[tok];
        f32x4 A0 = {0.f,0.f,0.f,0.f}, A1 = A0, A2 = A0, A3 = A0;
        #pragma unroll 8
        for (int s = 0; s < 128; s += 4) {
            A0 += *(const f32x4*)(Cp + (size_t)(s + 0) * DSZ) * snp[s + 0];
            A1 += *(const f32x4*)(Cp + (size_t)(s + 1) * DSZ) * snp[s + 1];
            A2 += *(const f32x4*)(Cp + (size_t)(s + 2) * DSZ) * snp[s + 2];
            A3 += *(const f32x4*)(Cp + (size_t)(s + 3) * DSZ) * snp[s + 3];
        }
        const f32x4 y4 = ((A0 + A1) + (A2 + A3)) * g_s[tok];
        ((f32x4*)(ybuf + (size_t)(slots[tok] * BSZ + toks[tok]) * DSZ + dcb))[dq] = y4;
    }
}

// ============ K_q: h3 reconstruct + q = h3 @ Wq + bq ============
// grid = 128 (tile = bid&31 -> 8 tokens, colq = bid>>5 -> 128 cols), 256 thr.
__global__ __launch_bounds__(256) void q_kernel(
    const float* __restrict__ hbuf,     // h2
    const float* __restrict__ ybuf,     // layer-2 gated y
    const float* __restrict__ gates2,   // [B][8]
    const float* __restrict__ Dsk2,     // [8][D]
    const float* __restrict__ Wq,       // [D][D]
    const float* __restrict__ bq,       // [D]
    float* __restrict__ q_out)          // [B][D]
{
    const int t = threadIdx.x;
    const int b0 = (blockIdx.x & 31) * 8;
    const int colb = (blockIdx.x >> 5) * 128;

    __shared__ float h_s[8 * HPAD];
    __shared__ float dsk_s[ENUM * DSZ];
    __shared__ float gprev_s[8 * ENUM];

    for (int i = t; i < 1024; i += 256) ((f32x4*)dsk_s)[i] = ((const f32x4*)Dsk2)[i];
    if (t < 64) gprev_s[t] = gates2[b0 * ENUM + t];
    __syncthreads();

    for (int i = t; i < 1024; i += 256) {
        const int tok = i >> 7, dq = i & 127;
        const int b = b0 + tok;
        f32x4 hq = ((const f32x4*)(hbuf + (size_t)b * DSZ))[dq];
        f32x4 w = {0.f, 0.f, 0.f, 0.f};
        #pragma unroll
        for (int e = 0; e < ENUM; ++e)
            w += ((const f32x4*)(dsk_s + e * DSZ))[dq] * gprev_s[tok * ENUM + e];
        hq = hq + hq * w
           + ((const f32x4*)(ybuf + (size_t)b * DSZ))[dq]
           + ((const f32x4*)(ybuf + (size_t)(BSZ + b) * DSZ))[dq];
        *(f32x4*)(h_s + tok * HPAD + dq * 4) = hq;
    }
    __syncthreads();

    // GEMM: thread (tok = t>>5, cq = t&31): col = colb + cq*4, K=512
    const int tok = t >> 5, cq = t & 31;
    const float* hp = h_s + tok * HPAD;
    const float* Wp = Wq + colb + cq * 4;
    f32x4 A0 = {0.f,0.f,0.f,0.f}, A1 = A0, A2 = A0, A3 = A0;
    #pragma unroll 8
    for (int d = 0; d < 512; d += 4) {
        A0 += *(const f32x4*)(Wp + (size_t)(d + 0) * DSZ) * hp[d + 0];
        A1 += *(const f32x4*)(Wp + (size_t)(d + 1) * DSZ) * hp[d + 1];
        A2 += *(const f32x4*)(Wp + (size_t)(d + 2) * DSZ) * hp[d + 2];
        A3 += *(const f32x4*)(Wp + (size_t)(d + 3) * DSZ) * hp[d + 3];
    }
    f32x4 q4 = (A0 + A1) + (A2 + A3);
    q4 += *(const f32x4*)(bq + colb + cq * 4);
    ((f32x4*)(q_out + (size_t)(b0 + tok) * DSZ))[colb / 4 + cq] = q4;
}

// ============ logits + lb_loss ============
// grid = (8, B), block = 256 (4 waves); wave: 32 n's processed in pairs.
__global__ __launch_bounds__(256) void logits_kernel(
    const float* __restrict__ q, const float* __restrict__ node_emb,
    float* __restrict__ logits,
    const float* __restrict__ acc, float* __restrict__ loss_out)
{
    const int b = blockIdx.y;
    const int wave = threadIdx.x >> 6;
    const int lane = threadIdx.x & 63;

    if (blockIdx.x == 0 && blockIdx.y == 0 && threadIdx.x == 0) {
        float lb = 0.f;
        for (int l = 0; l < LNUM; ++l)
            for (int e = 0; e < ENUM; ++e) {
                const float mp = acc[l * 16 + e] * (1.0f / BSZ);
                const float ms = acc[l * 16 + 8 + e] * (1.0f / BSZ);
                lb += (float)ENUM * mp * ms;
            }
        loss_out[0] = lb;
    }

    const f32x4* q4 = (const f32x4*)(q + b * DSZ);
    const f32x4 q0 = q4[lane];
    const f32x4 q1 = q4[lane + 64];
    const float scale = 0.04419417382415922f;  // 1/sqrt(512)

    const int n0 = blockIdx.x * 128 + wave * 32;
    for (int i = 0; i < 32; i += 2) {
        const f32x4* r0 = (const f32x4*)(node_emb + ((size_t)b * NSZ + n0 + i) * DSZ);
        const f32x4* r1 = (const f32x4*)(node_emb + ((size_t)b * NSZ + n0 + i + 1) * DSZ);
        const f32x4 a0 = __builtin_nontemporal_load(r0 + lane);
        const f32x4 a1 = __builtin_nontemporal_load(r0 + lane + 64);
        const f32x4 c0 = __builtin_nontemporal_load(r1 + lane);
        const f32x4 c1 = __builtin_nontemporal_load(r1 + lane + 64);
        float d0 = a0.x*q0.x + a0.y*q0.y + a0.z*q0.z + a0.w*q0.w
                 + a1.x*q1.x + a1.y*q1.y + a1.z*q1.z + a1.w*q1.w;
        float d1 = c0.x*q0.x + c0.y*q0.y + c0.z*q0.z + c0.w*q0.w
                 + c1.x*q1.x + c1.y*q1.y + c1.z*q1.z + c1.w*q1.w;
        #pragma unroll
        for (int off = 32; off; off >>= 1) {
            d0 += __shfl_down(d0, off, 64);
            d1 += __shfl_down(d1, off, 64);
        }
        if (lane == 0) {
            logits[b * NSZ + n0 + i]     = d0 * scale;
            logits[b * NSZ + n0 + i + 1] = d1 * scale;
        }
    }
}

extern "C" void kernel_launch(void* const* d_in, const int* in_sizes, int n_in,
                              void* d_out, int out_size, void* d_ws, size_t ws_size,
                              hipStream_t stream) {
    const float* token    = (const float*)d_in[0];  // B,1,D
    const float* node_emb = (const float*)d_in[1];  // B,N,D
    const float* states   = (const float*)d_in[2];  // L,E,B,DS
    const float* Wg       = (const float*)d_in[3];  // L,D,E
    const float* bg       = (const float*)d_in[4];  // L,E
    const float* A        = (const float*)d_in[5];  // L,E,DS
    const float* Bin      = (const float*)d_in[6];  // L,E,D,DS
    const float* Cout     = (const float*)d_in[7];  // L,E,DS,D
    const float* Dsk      = (const float*)d_in[8];  // L,E,D
    const float* Wq       = (const float*)d_in[9];  // D,D
    const float* bq       = (const float*)d_in[10]; // D

    float* out_logits = (float*)d_out;                                  // B*N
    float* out_states = out_logits + (size_t)BSZ * NSZ;                 // L*E*B*DS
    float* out_loss   = out_states + (size_t)LNUM * ENUM * BSZ * SSZ;   // 1

    // workspace layout
    float* ws_q    = (float*)d_ws;                       // 131072
    float* hbuf    = ws_q + 131072;                      // 131072
    float* ybuf    = hbuf + 131072;                      // 262144
    float* gates   = ybuf + 262144;                      // 3*2048
    int*   cnt     = (int*)(gates + 6144);               // 32 ints (3*8 used)
    float* acc     = (float*)(cnt + 32);                 // 64 floats (48 used)
    int*   lists   = (int*)(acc + 64);                   // 3*2048 ints

    // one memset: cnt(128B) + acc(256B) contiguous = 384 B
    (void)hipMemsetAsync(cnt, 0, 384, stream);

    for (int l = 0; l < LNUM; ++l) {
        const float* Wg_l  = Wg + (size_t)l * DSZ * ENUM;
        const float* bg_l  = bg + (size_t)l * ENUM;
        const float* A_l   = A + (size_t)l * ENUM * SSZ;
        const float* Bin_l = Bin + (size_t)l * ENUM * DSZ * SSZ;
        const float* Cou_l = Cout + (size_t)l * ENUM * SSZ * DSZ;
        const float* st_l  = states + (size_t)l * ENUM * BSZ * SSZ;
        float* os_l        = out_states + (size_t)l * ENUM * BSZ * SSZ;
        float* gates_l     = gates + l * 2048;
        int*   cnt_l       = cnt + l * 8;
        int*   list_l      = lists + l * 2048;

        gate_kernel<<<32, 256, 0, stream>>>(
            (l == 0) ? token : hbuf,
            (l == 0) ? nullptr : ybuf,
            (l == 0) ? nullptr : gates + (l - 1) * 2048,
            (l == 0) ? nullptr : Dsk + (size_t)(l - 1) * ENUM * DSZ,
            hbuf, Wg_l, bg_l, st_l, os_l, gates_l, cnt_l, list_l,
            acc + l * 16, acc + l * 16 + 8);

        snew_kernel<<<256, 1024, 0, stream>>>(
            hbuf, A_l, Bin_l, st_l, os_l, cnt_l, list_l);

        y_kernel<<<256, 1024, 0, stream>>>(
            os_l, Cou_l, gates_l, ybuf, cnt_l, list_l);
    }

    q_kernel<<<128, 256, 0, stream>>>(
        hbuf, ybuf, gates + 2 * 2048, Dsk + (size_t)2 * ENUM * DSZ, Wq, bq, ws_q);

    dim3 lg(NSZ / 128, BSZ);
    logits_kernel<<<lg, 256, 0, stream>>>(ws_q, node_emb, out_logits, acc, out_loss);
}